// Round 1
// baseline (357.223 us; speedup 1.0000x reference)
//
#include <hip/hip_runtime.h>
#include <math.h>

#define NROWS 64
#define DCOLS 512
#define NKEY  63
#define BDIM  1024
#define RPW   4   // rows per wave: 64 rows / 16 waves

__device__ __forceinline__ void wave_reduce_sum2(float& a, float& b) {
#pragma unroll
    for (int off = 32; off > 0; off >>= 1) {
        a += __shfl_xor(a, off, 64);
        b += __shfl_xor(b, off, 64);
    }
}

__device__ __forceinline__ float wave_reduce_sum(float v) {
#pragma unroll
    for (int off = 32; off > 0; off >>= 1)
        v += __shfl_xor(v, off, 64);
    return v;
}

// tanh(x) = sign(x) * (1 - 2/(exp(2|x|)+1)); safe for large |x| (exp->inf -> 1)
__device__ __forceinline__ float fast_tanh(float x) {
    float ax = fabsf(x);
    float e  = __expf(2.0f * ax);
    float t  = 1.0f - 2.0f / (e + 1.0f);
    return copysignf(t, x);
}

__global__ __launch_bounds__(BDIM, 4) void fused_ln_attn_kernel(
    const float* __restrict__ emb,
    const float* __restrict__ gamma,
    const float* __restrict__ beta,
    const float* __restrict__ Wv,
    const float* __restrict__ bv,
    float* __restrict__ out)
{
    __shared__ float s_q[DCOLS];
    __shared__ float s_sc[NKEY + 1];

    const int b    = blockIdx.x;
    const int tid  = threadIdx.x;
    const int wave = tid >> 6;
    const int lane = tid & 63;
    const int c0   = lane << 2;          // columns [c0, c0+4)
    const int c1   = 256 + (lane << 2);  // columns [c1, c1+4)

    // per-column parameters (reused for all 64 rows)
    const float4 g0 = *(const float4*)(gamma + c0);
    const float4 g1 = *(const float4*)(gamma + c1);
    const float4 bb0 = *(const float4*)(beta + c0);
    const float4 bb1 = *(const float4*)(beta + c1);
    const float4 w0 = *(const float4*)(Wv + c0);
    const float4 w1 = *(const float4*)(Wv + c1);
    const float  bias = bv[0];

    const size_t base = (size_t)b * (size_t)(NROWS * DCOLS);
    const float* eb = emb + base;
    float*       ob = out + base;

    float4 e0[RPW], e1[RPW];

    // ---- Pass 1: LayerNorm each owned row, keep e in registers ----
#pragma unroll
    for (int i = 0; i < RPW; ++i) {
        const int r = wave * RPW + i;
        const float* rp = eb + r * DCOLS;
        const float4 x0 = *(const float4*)(rp + c0);
        const float4 x1 = *(const float4*)(rp + c1);

        float s  = ((x0.x + x0.y) + (x0.z + x0.w)) + ((x1.x + x1.y) + (x1.z + x1.w));
        float ss = (x0.x*x0.x + x0.y*x0.y + x0.z*x0.z + x0.w*x0.w)
                 + (x1.x*x1.x + x1.y*x1.y + x1.z*x1.z + x1.w*x1.w);
        wave_reduce_sum2(s, ss);

        const float mu  = s * (1.0f / (float)DCOLS);
        const float var = ss * (1.0f / (float)DCOLS) - mu * mu;
        const float rs  = rsqrtf(var + 1e-5f);

        float4 t0, t1;
        t0.x = (x0.x - mu) * rs * g0.x + bb0.x;
        t0.y = (x0.y - mu) * rs * g0.y + bb0.y;
        t0.z = (x0.z - mu) * rs * g0.z + bb0.z;
        t0.w = (x0.w - mu) * rs * g0.w + bb0.w;
        t1.x = (x1.x - mu) * rs * g1.x + bb1.x;
        t1.y = (x1.y - mu) * rs * g1.y + bb1.y;
        t1.z = (x1.z - mu) * rs * g1.z + bb1.z;
        t1.w = (x1.w - mu) * rs * g1.w + bb1.w;
        e0[i] = t0;
        e1[i] = t1;
    }

    // row 0 (query): stash in LDS for all waves + write straight to output
    if (wave == 0) {
        *(float4*)(s_q + c0) = e0[0];
        *(float4*)(s_q + c1) = e1[0];
        *(float4*)(ob + c0) = e0[0];
        *(float4*)(ob + c1) = e1[0];
    }
    __syncthreads();

    const float4 q0 = *(const float4*)(s_q + c0);
    const float4 q1 = *(const float4*)(s_q + c1);

    // ---- Pass 2: scores_r = sum_d tanh(q_d * e_rd) * Wv_d + bv ----
    float sc[RPW];
#pragma unroll
    for (int i = 0; i < RPW; ++i) {
        const int r = wave * RPW + i;
        float p = 0.0f;
        if (r > 0) {
            p  = fast_tanh(q0.x * e0[i].x) * w0.x;
            p += fast_tanh(q0.y * e0[i].y) * w0.y;
            p += fast_tanh(q0.z * e0[i].z) * w0.z;
            p += fast_tanh(q0.w * e0[i].w) * w0.w;
            p += fast_tanh(q1.x * e1[i].x) * w1.x;
            p += fast_tanh(q1.y * e1[i].y) * w1.y;
            p += fast_tanh(q1.z * e1[i].z) * w1.z;
            p += fast_tanh(q1.w * e1[i].w) * w1.w;
        }
        const float tot = wave_reduce_sum(p) + bias;
        sc[i] = tot;
        if (lane == 0 && r > 0) s_sc[r - 1] = tot;
    }
    __syncthreads();

    // ---- Softmax stats (redundant per thread; LDS same-address reads broadcast) ----
    float m = -1e30f;
#pragma unroll 1
    for (int k = 0; k < NKEY; ++k) m = fmaxf(m, s_sc[k]);
    float den = 0.0f;
#pragma unroll 1
    for (int k = 0; k < NKEY; ++k) den += __expf(s_sc[k] - m);
    const float inv = 1.0f / den;

    // ---- Pass 3: out_r = alpha_r * e_r for key rows ----
#pragma unroll
    for (int i = 0; i < RPW; ++i) {
        const int r = wave * RPW + i;
        if (r == 0) continue;
        const float a = __expf(sc[i] - m) * inv;
        float4 o0, o1;
        o0.x = a * e0[i].x; o0.y = a * e0[i].y; o0.z = a * e0[i].z; o0.w = a * e0[i].w;
        o1.x = a * e1[i].x; o1.y = a * e1[i].y; o1.z = a * e1[i].z; o1.w = a * e1[i].w;
        *(float4*)(ob + r * DCOLS + c0) = o0;
        *(float4*)(ob + r * DCOLS + c1) = o1;
    }
}

extern "C" void kernel_launch(void* const* d_in, const int* in_sizes, int n_in,
                              void* d_out, int out_size, void* d_ws, size_t ws_size,
                              hipStream_t stream) {
    const float* emb   = (const float*)d_in[0];
    const float* gamma = (const float*)d_in[1];
    const float* beta  = (const float*)d_in[2];
    const float* Wv    = (const float*)d_in[3];
    const float* bv    = (const float*)d_in[4];
    float* out = (float*)d_out;

    const int B = in_sizes[0] / (NROWS * DCOLS);
    fused_ln_attn_kernel<<<B, BDIM, 0, stream>>>(emb, gamma, beta, Wv, bv, out);
}

// Round 3
// 264.586 us; speedup vs baseline: 1.3501x; 1.3501x over previous
//
#include <hip/hip_runtime.h>
#include <math.h>

#define NROWS 64
#define DCOLS 512
#define NKEY  63
#define BDIM  1024
#define RPW   4   // rows per wave: 64 rows / 16 waves

typedef float f32x4 __attribute__((ext_vector_type(4)));

__device__ __forceinline__ void nt_store4(float* p, float4 v) {
    f32x4 t;
    t.x = v.x; t.y = v.y; t.z = v.z; t.w = v.w;
    __builtin_nontemporal_store(t, (f32x4*)p);
}

__device__ __forceinline__ void wave_reduce_sum2(float& a, float& b) {
#pragma unroll
    for (int off = 32; off > 0; off >>= 1) {
        a += __shfl_xor(a, off, 64);
        b += __shfl_xor(b, off, 64);
    }
}

__device__ __forceinline__ float wave_reduce_sum(float v) {
#pragma unroll
    for (int off = 32; off > 0; off >>= 1)
        v += __shfl_xor(v, off, 64);
    return v;
}

__device__ __forceinline__ float wave_reduce_max(float v) {
#pragma unroll
    for (int off = 32; off > 0; off >>= 1)
        v = fmaxf(v, __shfl_xor(v, off, 64));
    return v;
}

// tanh(x) = sign(x) * (1 - 2/(exp(2|x|)+1)); safe for large |x| (exp->inf -> 1)
__device__ __forceinline__ float fast_tanh(float x) {
    float ax = fabsf(x);
    float e  = __expf(2.0f * ax);
    float t  = 1.0f - 2.0f / (e + 1.0f);
    return copysignf(t, x);
}

__global__ __launch_bounds__(BDIM, 4) void fused_ln_attn_kernel(
    const float* __restrict__ emb,
    const float* __restrict__ gamma,
    const float* __restrict__ beta,
    const float* __restrict__ Wv,
    const float* __restrict__ bv,
    float* __restrict__ out)
{
    __shared__ float s_q[DCOLS];
    __shared__ float s_sc[NROWS];   // scores for rows 1..63 at index r
    __shared__ float s_stats[2];    // m, 1/den

    const int b    = blockIdx.x;
    const int tid  = threadIdx.x;
    const int wave = tid >> 6;
    const int lane = tid & 63;
    const int c0   = lane << 2;          // columns [c0, c0+4)
    const int c1   = 256 + (lane << 2);  // columns [c1, c1+4)

    // per-column parameters (reused for all 64 rows)
    const float4 g0  = *(const float4*)(gamma + c0);
    const float4 g1  = *(const float4*)(gamma + c1);
    const float4 bb0 = *(const float4*)(beta + c0);
    const float4 bb1 = *(const float4*)(beta + c1);
    const float4 w0  = *(const float4*)(Wv + c0);
    const float4 w1  = *(const float4*)(Wv + c1);
    const float  bias = bv[0];

    const size_t base = (size_t)b * (size_t)(NROWS * DCOLS);
    const float* eb = emb + base;
    float*       ob = out + base;

    float4 e0[RPW], e1[RPW];

    // ---- Pass 1: LayerNorm each owned row, keep e in registers ----
#pragma unroll
    for (int i = 0; i < RPW; ++i) {
        const int r = wave * RPW + i;
        const float* rp = eb + r * DCOLS;
        const float4 x0 = *(const float4*)(rp + c0);
        const float4 x1 = *(const float4*)(rp + c1);

        float s  = ((x0.x + x0.y) + (x0.z + x0.w)) + ((x1.x + x1.y) + (x1.z + x1.w));
        float ss = (x0.x*x0.x + x0.y*x0.y + x0.z*x0.z + x0.w*x0.w)
                 + (x1.x*x1.x + x1.y*x1.y + x1.z*x1.z + x1.w*x1.w);
        wave_reduce_sum2(s, ss);

        const float mu  = s * (1.0f / (float)DCOLS);
        const float var = ss * (1.0f / (float)DCOLS) - mu * mu;
        const float rs  = rsqrtf(var + 1e-5f);

        float4 t0, t1;
        t0.x = (x0.x - mu) * rs * g0.x + bb0.x;
        t0.y = (x0.y - mu) * rs * g0.y + bb0.y;
        t0.z = (x0.z - mu) * rs * g0.z + bb0.z;
        t0.w = (x0.w - mu) * rs * g0.w + bb0.w;
        t1.x = (x1.x - mu) * rs * g1.x + bb1.x;
        t1.y = (x1.y - mu) * rs * g1.y + bb1.y;
        t1.z = (x1.z - mu) * rs * g1.z + bb1.z;
        t1.w = (x1.w - mu) * rs * g1.w + bb1.w;
        e0[i] = t0;
        e1[i] = t1;
    }

    // row 0 (query): stash in LDS for all waves + write straight to output
    if (wave == 0) {
        *(float4*)(s_q + c0) = e0[0];
        *(float4*)(s_q + c1) = e1[0];
        nt_store4(ob + c0, e0[0]);
        nt_store4(ob + c1, e1[0]);
    }
    __syncthreads();

    const float4 q0 = *(const float4*)(s_q + c0);
    const float4 q1 = *(const float4*)(s_q + c1);

    // ---- Pass 2: scores_r = sum_d tanh(q_d * e_rd) * Wv_d + bv ----
    float sc[RPW];
#pragma unroll
    for (int i = 0; i < RPW; ++i) {
        const int r = wave * RPW + i;
        float p = 0.0f;
        if (r > 0) {
            p  = fast_tanh(q0.x * e0[i].x) * w0.x;
            p += fast_tanh(q0.y * e0[i].y) * w0.y;
            p += fast_tanh(q0.z * e0[i].z) * w0.z;
            p += fast_tanh(q0.w * e0[i].w) * w0.w;
            p += fast_tanh(q1.x * e1[i].x) * w1.x;
            p += fast_tanh(q1.y * e1[i].y) * w1.y;
            p += fast_tanh(q1.z * e1[i].z) * w1.z;
            p += fast_tanh(q1.w * e1[i].w) * w1.w;
        }
        const float tot = wave_reduce_sum(p) + bias;
        sc[i] = tot;
        if (lane == 0 && r > 0) s_sc[r] = tot;
    }
    __syncthreads();

    // ---- Softmax stats: ONE wave does a parallel reduce over the 63 scores ----
    if (wave == 0) {
        const float v  = (lane >= 1) ? s_sc[lane] : -1e30f;  // lanes 1..63 hold rows 1..63
        const float m  = wave_reduce_max(v);
        const float ex = (lane >= 1) ? __expf(v - m) : 0.0f;
        const float dn = wave_reduce_sum(ex);
        if (lane == 0) {
            s_stats[0] = m;
            s_stats[1] = 1.0f / dn;
        }
    }
    __syncthreads();

    const float m   = s_stats[0];
    const float inv = s_stats[1];

    // ---- Pass 3: out_r = alpha_r * e_r for key rows ----
#pragma unroll
    for (int i = 0; i < RPW; ++i) {
        const int r = wave * RPW + i;
        if (r == 0) continue;
        const float a = __expf(sc[i] - m) * inv;
        float4 o0, o1;
        o0.x = a * e0[i].x; o0.y = a * e0[i].y; o0.z = a * e0[i].z; o0.w = a * e0[i].w;
        o1.x = a * e1[i].x; o1.y = a * e1[i].y; o1.z = a * e1[i].z; o1.w = a * e1[i].w;
        nt_store4(ob + r * DCOLS + c0, o0);
        nt_store4(ob + r * DCOLS + c1, o1);
    }
}

extern "C" void kernel_launch(void* const* d_in, const int* in_sizes, int n_in,
                              void* d_out, int out_size, void* d_ws, size_t ws_size,
                              hipStream_t stream) {
    const float* emb   = (const float*)d_in[0];
    const float* gamma = (const float*)d_in[1];
    const float* beta  = (const float*)d_in[2];
    const float* Wv    = (const float*)d_in[3];
    const float* bv    = (const float*)d_in[4];
    float* out = (float*)d_out;

    const int B = in_sizes[0] / (NROWS * DCOLS);
    fused_ln_attn_kernel<<<B, BDIM, 0, stream>>>(emb, gamma, beta, Wv, bv, out);
}